// Round 6
// baseline (568.810 us; speedup 1.0000x reference)
//
#include <hip/hip_runtime.h>
#include <hip/hip_bf16.h>
#include <stdint.h>

// GraphConv (GCN layer), N=100000, E=1.6M, D=256, f32 in/out.
// Pipeline (project-then-aggregate; aggregation is linear):
//   1. k_deg:  degree counts (int atomics, 4 edges/thread, int4 loads)
//   2. k_off:  CSR bucket bases via per-block LDS scan + atomic base (order-free)
//   3. k_fill: bucket src ids by dst via atomic cursor (4 edges/thread)
//   4. k_wt:   WT[n][k] = bf16(W[k][n])
//   5. k_gemm: z = bf16(feat*pre) @ W, LDS-staged WT (2 K-halves, XOR-swizzled),
//              z stored in NATURAL layout (scalar 2B stores, block-covered)
//   6. k_agg:  out[n] = rsqrt(max(indeg,1)) * sum_{in-edges} z[src] + bias
//              2 column passes (gridDim.y), quarter-wave per edge (4 edges/instr),
//              2-deep gather pipeline, nontemporal contiguous out stores

using short8  = __attribute__((ext_vector_type(8))) short;
using floatx4 = __attribute__((ext_vector_type(4))) float;
using floatx2 = __attribute__((ext_vector_type(2))) float;
using ushort8 = __attribute__((ext_vector_type(8))) unsigned short;

static __device__ __forceinline__ unsigned short f32_to_bf16(float f) {
    unsigned int u = __float_as_uint(f);
    u += 0x7FFFu + ((u >> 16) & 1u);   // round-to-nearest-even
    return (unsigned short)(u >> 16);
}
static __device__ __forceinline__ float bf2f(unsigned short u) {
    return __uint_as_float((unsigned int)u << 16);
}

__global__ void k_deg(const int* __restrict__ src, const int* __restrict__ dst,
                      int E, int* __restrict__ outc, int* __restrict__ inc) {
    int i = blockIdx.x * blockDim.x + threadIdx.x;
    int b = i * 4;
    if (b + 3 < E) {
        int4 s = *(const int4*)(src + b);
        int4 d = *(const int4*)(dst + b);
        atomicAdd(&outc[s.x], 1);
        atomicAdd(&outc[s.y], 1);
        atomicAdd(&outc[s.z], 1);
        atomicAdd(&outc[s.w], 1);
        atomicAdd(&inc[d.x], 1);
        atomicAdd(&inc[d.y], 1);
        atomicAdd(&inc[d.z], 1);
        atomicAdd(&inc[d.w], 1);
    } else {
        for (int j = b; j < E; ++j) {
            atomicAdd(&outc[src[j]], 1);
            atomicAdd(&inc[dst[j]], 1);
        }
    }
}

// per-block exclusive scan + atomic global base -> cursor (bucket order across
// blocks arbitrary; only base[n] / base[n]+deg[n] consistency matters)
__global__ void k_off(const int* __restrict__ inc, int N, int* __restrict__ total,
                      int* __restrict__ cursor) {
    __shared__ int ss[256];
    __shared__ int sbase;
    int t = threadIdx.x;
    int i = blockIdx.x * 256 + t;
    int d = (i < N) ? inc[i] : 0;
    int v = d;
    ss[t] = v;
    __syncthreads();
    for (int off = 1; off < 256; off <<= 1) {
        int u = (t >= off) ? ss[t - off] : 0;
        __syncthreads();
        v += u;
        ss[t] = v;
        __syncthreads();
    }
    if (t == 255) sbase = atomicAdd(total, v);   // v = block sum
    __syncthreads();
    if (i < N) cursor[i] = sbase + (v - d);      // exclusive prefix
}

__global__ void k_fill(const int* __restrict__ src, const int* __restrict__ dst,
                       int E, int* __restrict__ cursor, int* __restrict__ eidx) {
    int i = blockIdx.x * blockDim.x + threadIdx.x;
    int b = i * 4;
    if (b + 3 < E) {
        int4 s = *(const int4*)(src + b);
        int4 d = *(const int4*)(dst + b);
        int p0 = atomicAdd(&cursor[d.x], 1);   // 4 independent returning atomics
        int p1 = atomicAdd(&cursor[d.y], 1);
        int p2 = atomicAdd(&cursor[d.z], 1);
        int p3 = atomicAdd(&cursor[d.w], 1);
        eidx[p0] = s.x;
        eidx[p1] = s.y;
        eidx[p2] = s.z;
        eidx[p3] = s.w;
    } else {
        for (int j = b; j < E; ++j) {
            int p = atomicAdd(&cursor[dst[j]], 1);
            eidx[p] = src[j];
        }
    }
}

// WT[n*256+k] = bf16(W[k*256+n])
__global__ void k_wt(const float* __restrict__ W, unsigned short* __restrict__ WT) {
    int i = blockIdx.x * blockDim.x + threadIdx.x;   // 65536 threads
    int n = i >> 8, k = i & 255;
    WT[n * 256 + k] = f32_to_bf16(W[(size_t)k * 256 + n]);
}

// z = bf16(feat*pre) @ W. Block: 512 thr (8 waves) x 128 rows x 256 cols.
// WT staged in 64KB LDS per K-half, XOR-swizzled (byte ^= (row&7)<<4).
// z stored in NATURAL layout: z[row][col], scalar 2B stores (block-covered).
__global__ void __launch_bounds__(512, 4)
k_gemm(const float* __restrict__ feat, const int* __restrict__ outc,
       const unsigned short* __restrict__ WT, int N,
       unsigned short* __restrict__ z) {
    __shared__ unsigned short ldsB[256 * 128];   // [ncol 256][khalf 128] bf16, swizzled

    int tid  = threadIdx.x;
    int wave = tid >> 6;
    int lane = tid & 63;
    int rl   = lane & 15;        // A row / B col within 16
    int g    = lane >> 4;        // k-group 0..3
    int wm0  = blockIdx.x * 128 + wave * 16;
    int rowc = min(wm0 + rl, N - 1);
    float p  = rsqrtf((float)max(outc[rowc], 1));
    const floatx4* arow = (const floatx4*)(feat + (size_t)rowc * 256);
    int smask = (rl & 7) << 4;   // per-lane swizzle mask (n*16 preserves row&7)

    floatx4 acc[16];
#pragma unroll
    for (int n = 0; n < 16; ++n) acc[n] = (floatx4){0.f, 0.f, 0.f, 0.f};

#pragma unroll
    for (int h = 0; h < 2; ++h) {
        if (h) __syncthreads();          // phase-0 reads done before restage
        // stage: 4096 16B-chunks, 8 per thread, coalesced global -> swizzled LDS
#pragma unroll
        for (int i = 0; i < 8; ++i) {
            int c    = i * 512 + tid;
            int r2   = c >> 4;                  // n-row 0..255
            int colb = (c & 15) << 4;           // byte col 0..240
            ushort8 v = *(const ushort8*)(WT + r2 * 256 + h * 128 + (colb >> 1));
            int dst = r2 * 128 + ((colb ^ ((r2 & 7) << 4)) >> 1);
            *(ushort8*)(&ldsB[dst]) = v;
        }
        __syncthreads();

#pragma unroll
        for (int k2 = 0; k2 < 4; ++k2) {
            floatx4 v0 = __builtin_nontemporal_load(arow + h * 32 + k2 * 8 + g * 2);
            floatx4 v1 = __builtin_nontemporal_load(arow + h * 32 + k2 * 8 + g * 2 + 1);
            short8 a;
            a[0] = (short)f32_to_bf16(v0[0] * p);
            a[1] = (short)f32_to_bf16(v0[1] * p);
            a[2] = (short)f32_to_bf16(v0[2] * p);
            a[3] = (short)f32_to_bf16(v0[3] * p);
            a[4] = (short)f32_to_bf16(v1[0] * p);
            a[5] = (short)f32_to_bf16(v1[1] * p);
            a[6] = (short)f32_to_bf16(v1[2] * p);
            a[7] = (short)f32_to_bf16(v1[3] * p);
            int cb = (k2 * 64 + g * 16) ^ smask;    // swizzled byte col
#pragma unroll
            for (int n = 0; n < 16; ++n) {
                short8 b = *(const short8*)(&ldsB[(n * 16 + rl) * 128 + (cb >> 1)]);
                acc[n] = __builtin_amdgcn_mfma_f32_16x16x32_bf16(a, b, acc[n], 0, 0, 0);
            }
        }
    }

    // epilogue: lane (rl,g) holds rows wm0+g*4+i, cols n*16+rl -> natural layout
#pragma unroll
    for (int n = 0; n < 16; ++n) {
        int c = n * 16 + rl;
#pragma unroll
        for (int i = 0; i < 4; ++i) {
            int rw = wm0 + g * 4 + i;
            if (rw < N) z[(size_t)rw * 256 + c] = f32_to_bf16(acc[n][i]);
        }
    }
}

// out[n] = rsqrt(max(deg,1)) * sum z[src] + bias; one wave per (node, col-half).
// gridDim.y = 2 column passes; quarter-wave per edge: 16 lanes x 16B = 256B half-row.
__global__ void k_agg(const unsigned short* __restrict__ z,
                      const int* __restrict__ cursor, const int* __restrict__ inc,
                      const int* __restrict__ eidx, const float* __restrict__ bias,
                      int N, float* __restrict__ out) {
    int node = blockIdx.x * 4 + (threadIdx.x >> 6);
    if (node >= N) return;
    int h    = blockIdx.y;           // column pass: cols h*128 .. h*128+127
    int lane = threadIdx.x & 63;
    int q    = lane >> 4;            // quarter 0..3 -> edge e+q
    int sl   = lane & 15;            // 16B chunk within the 256B half-row
    int deg  = inc[node];
    const int* ep = eidx + (cursor[node] - deg);   // cursor is END after k_fill
    const unsigned short* zh = z + h * 128 + sl * 8;

    float accA[8], accB[8];
#pragma unroll
    for (int j = 0; j < 8; ++j) { accA[j] = 0.f; accB[j] = 0.f; }

    int e = 0;
    for (; e + 8 <= deg; e += 8) {       // 8 edges, 2 gathers in flight
        int s0 = ep[e + q];
        int s1 = ep[e + 4 + q];
        ushort8 v0 = *(const ushort8*)(zh + (size_t)s0 * 256);
        ushort8 v1 = *(const ushort8*)(zh + (size_t)s1 * 256);
#pragma unroll
        for (int j = 0; j < 8; ++j) {
            accA[j] += bf2f(v0[j]);
            accB[j] += bf2f(v1[j]);
        }
    }
    for (; e < deg; e += 4) {            // tail: predicated quarters
        if (e + q < deg) {
            int s = ep[e + q];
            ushort8 v = *(const ushort8*)(zh + (size_t)s * 256);
#pragma unroll
            for (int j = 0; j < 8; ++j) accA[j] += bf2f(v[j]);
        }
    }
#pragma unroll
    for (int j = 0; j < 8; ++j) accA[j] += accB[j];
    // reduce across quarters (fixed sl): all lanes end with the full sum
#pragma unroll
    for (int j = 0; j < 8; ++j) accA[j] += __shfl_xor(accA[j], 16);
#pragma unroll
    for (int j = 0; j < 8; ++j) accA[j] += __shfl_xor(accA[j], 32);

    float post = rsqrtf((float)max(deg, 1));
    // lane (q,sl) writes cols h*128 + sl*8 + q*2 + {0,1}  -> contiguous per wave
    int c = h * 128 + sl * 8 + q * 2;
    floatx2 o;
    o[0] = accA[q * 2 + 0] * post + bias[c];
    o[1] = accA[q * 2 + 1] * post + bias[c + 1];
    __builtin_nontemporal_store(o, (floatx2*)(out + (size_t)node * 256 + c));
}

extern "C" void kernel_launch(void* const* d_in, const int* in_sizes, int n_in,
                              void* d_out, int out_size, void* d_ws, size_t ws_size,
                              hipStream_t stream) {
    const float* feat = (const float*)d_in[0];
    const int*   src  = (const int*)d_in[1];
    const int*   dst  = (const int*)d_in[2];
    const float* W    = (const float*)d_in[3];
    const float* bias = (const float*)d_in[4];
    float* out = (float*)d_out;

    const int D = 256;
    int N = in_sizes[0] / D;   // 100000
    int E = in_sizes[1];       // 1600000

    // workspace layout (256B aligned chunks), total ~58 MB
    char* ws = (char*)d_ws;
    size_t off = 0;
    auto alloc = [&](size_t bytes) -> void* {
        void* p = ws + off;
        off += (bytes + 255) & ~(size_t)255;
        return p;
    };
    int*            cnt    = (int*)alloc(((size_t)2 * N + 64) * sizeof(int)); // outc|inc|total
    int*            outc   = cnt;
    int*            inc    = cnt + N;
    int*            total  = cnt + 2 * N;
    int*            cursor = (int*)alloc((size_t)N * sizeof(int));
    int*            eidx   = (int*)alloc((size_t)E * sizeof(int));
    unsigned short* z      = (unsigned short*)alloc((size_t)N * D * sizeof(unsigned short));
    unsigned short* WT     = (unsigned short*)alloc((size_t)D * D * sizeof(unsigned short));
    (void)ws_size;

    hipMemsetAsync(cnt, 0, ((size_t)2 * N + 64) * sizeof(int), stream);

    int tE4 = (E + 3) / 4;   // threads for 4-edges-per-thread kernels
    k_deg <<<(tE4 + 255) / 256, 256, 0, stream>>>(src, dst, E, outc, inc);
    k_off <<<(N + 255) / 256, 256, 0, stream>>>(inc, N, total, cursor);
    k_fill<<<(tE4 + 255) / 256, 256, 0, stream>>>(src, dst, E, cursor, eidx);
    k_wt  <<<(D * D) / 256, 256, 0, stream>>>(W, WT);
    k_gemm<<<(N + 127) / 128, 512, 0, stream>>>(feat, outc, WT, N, z);
    k_agg <<<dim3((N + 3) / 4, 2), 256, 0, stream>>>(z, cursor, inc, eidx, bias, N, out);
}

// Round 7
// 555.068 us; speedup vs baseline: 1.0248x; 1.0248x over previous
//
#include <hip/hip_runtime.h>
#include <hip/hip_bf16.h>
#include <stdint.h>

// GraphConv (GCN layer), N=100000, E=1.6M, D=256, f32 in/out.
// Pipeline (project-then-aggregate; aggregation is linear):
//   1. k_deg:  degree counts (int atomics, 2 edges/thread, 2 coalesced streams)
//   2. k_off:  CSR bucket bases via per-block LDS scan + atomic base (order-free)
//   3. k_wt:   WT[n][k] = bf16(W[k][n])
//   4. k_fg:   FUSED fill+gemm. Fill blocks (first): bucket src by dst via atomic
//              cursor (atomic-latency-bound). Gemm blocks: z = bf16(feat*pre) @ W,
//              WT staged in 32KB LDS (4 K-quarters, XOR-swizzled), natural z layout.
//              Disjoint resources -> gemm hides under fill latency.
//   5. k_agg:  out[n] = rsqrt(max(indeg,1)) * sum_{in-edges} z[src] + bias
//              2 column passes (gridDim.y), quarter-wave per edge, 2-deep pipeline.

using short8  = __attribute__((ext_vector_type(8))) short;
using floatx4 = __attribute__((ext_vector_type(4))) float;
using floatx2 = __attribute__((ext_vector_type(2))) float;
using ushort8 = __attribute__((ext_vector_type(8))) unsigned short;

static __device__ __forceinline__ unsigned short f32_to_bf16(float f) {
    unsigned int u = __float_as_uint(f);
    u += 0x7FFFu + ((u >> 16) & 1u);   // round-to-nearest-even
    return (unsigned short)(u >> 16);
}
static __device__ __forceinline__ float bf2f(unsigned short u) {
    return __uint_as_float((unsigned int)u << 16);
}

__global__ void k_deg(const int* __restrict__ src, const int* __restrict__ dst,
                      int E, int* __restrict__ outc, int* __restrict__ inc) {
    int base = blockIdx.x * 512;
    int e0 = base + threadIdx.x;
    int e1 = e0 + 256;
    if (e0 < E) {
        int s0 = src[e0], d0 = dst[e0];
        atomicAdd(&outc[s0], 1);
        atomicAdd(&inc[d0], 1);
    }
    if (e1 < E) {
        int s1 = src[e1], d1 = dst[e1];
        atomicAdd(&outc[s1], 1);
        atomicAdd(&inc[d1], 1);
    }
}

// per-block exclusive scan + atomic global base -> cursor (bucket order across
// blocks arbitrary; only base[n] / base[n]+deg[n] consistency matters)
__global__ void k_off(const int* __restrict__ inc, int N, int* __restrict__ total,
                      int* __restrict__ cursor) {
    __shared__ int ss[256];
    __shared__ int sbase;
    int t = threadIdx.x;
    int i = blockIdx.x * 256 + t;
    int d = (i < N) ? inc[i] : 0;
    int v = d;
    ss[t] = v;
    __syncthreads();
    for (int off = 1; off < 256; off <<= 1) {
        int u = (t >= off) ? ss[t - off] : 0;
        __syncthreads();
        v += u;
        ss[t] = v;
        __syncthreads();
    }
    if (t == 255) sbase = atomicAdd(total, v);   // v = block sum
    __syncthreads();
    if (i < N) cursor[i] = sbase + (v - d);      // exclusive prefix
}

// WT[n*256+k] = bf16(W[k*256+n])
__global__ void k_wt(const float* __restrict__ W, unsigned short* __restrict__ WT) {
    int i = blockIdx.x * blockDim.x + threadIdx.x;   // 65536 threads
    int n = i >> 8, k = i & 255;
    WT[n * 256 + k] = f32_to_bf16(W[(size_t)k * 256 + n]);
}

// Fused fill+gemm. Blocks [0, nbFill): fill (2 edges/thread, 512 thr).
// Blocks [nbFill, ...): gemm, 128 rows x 256 cols per block, 8 waves.
// Gemm LDS: 32KB, WT staged in 4 K-quarters of 64 cols, XOR-swizzled.
__global__ void __launch_bounds__(512)
k_fg(const int* __restrict__ src, const int* __restrict__ dst, int E,
     int* __restrict__ cursor, int* __restrict__ eidx,
     const float* __restrict__ feat, const int* __restrict__ outc,
     const unsigned short* __restrict__ WT, int N, unsigned short* __restrict__ z,
     int nbFill) {
    __shared__ unsigned short ldsB[256 * 64];   // [ncol 256][kquarter 64] bf16, swizzled

    int tid = threadIdx.x;

    if ((int)blockIdx.x < nbFill) {
        // ---- fill part: 1024 edges/block, two coalesced streams ----
        int base = blockIdx.x * 1024;
        int e0 = base + tid;
        int e1 = e0 + 512;
        if (e0 < E) {
            int s0 = src[e0];
            int p0 = atomicAdd(&cursor[dst[e0]], 1);
            eidx[p0] = s0;
        }
        if (e1 < E) {
            int s1 = src[e1];
            int p1 = atomicAdd(&cursor[dst[e1]], 1);
            eidx[p1] = s1;
        }
        return;
    }

    // ---- gemm part ----
    int gbid = blockIdx.x - nbFill;
    int wave = tid >> 6;
    int lane = tid & 63;
    int rl   = lane & 15;        // A row / B col within 16
    int g    = lane >> 4;        // k-group 0..3
    int wm0  = gbid * 128 + wave * 16;
    int rowc = min(wm0 + rl, N - 1);
    float p  = rsqrtf((float)max(outc[rowc], 1));
    const floatx4* arow = (const floatx4*)(feat + (size_t)rowc * 256);
    int smask = (rl & 7) << 4;   // per-lane swizzle mask (row = n*16+rl, n*16 preserves row&7)

    floatx4 acc[16];
#pragma unroll
    for (int n = 0; n < 16; ++n) acc[n] = (floatx4){0.f, 0.f, 0.f, 0.f};

#pragma unroll
    for (int h = 0; h < 4; ++h) {
        if (h) __syncthreads();          // previous quarter's reads done
        // stage quarter h: 256 rows x 64 cols (128B/row), 2048 16B-chunks, 4/thread
#pragma unroll
        for (int i = 0; i < 4; ++i) {
            int c    = i * 512 + tid;
            int r2   = c >> 3;                  // n-row 0..255
            int colb = (c & 7) << 4;            // byte col 0..112
            ushort8 v = *(const ushort8*)(WT + r2 * 256 + h * 64 + (colb >> 1));
            int dstb = r2 * 64 + (((colb ^ ((r2 & 7) << 4))) >> 1);
            *(ushort8*)(&ldsB[dstb]) = v;
        }
        __syncthreads();

#pragma unroll
        for (int kk = 0; kk < 2; ++kk) {    // two 32-col k-steps per quarter
            floatx4 v0 = __builtin_nontemporal_load(arow + h * 16 + kk * 8 + g * 2);
            floatx4 v1 = __builtin_nontemporal_load(arow + h * 16 + kk * 8 + g * 2 + 1);
            short8 a;
            a[0] = (short)f32_to_bf16(v0[0] * p);
            a[1] = (short)f32_to_bf16(v0[1] * p);
            a[2] = (short)f32_to_bf16(v0[2] * p);
            a[3] = (short)f32_to_bf16(v0[3] * p);
            a[4] = (short)f32_to_bf16(v1[0] * p);
            a[5] = (short)f32_to_bf16(v1[1] * p);
            a[6] = (short)f32_to_bf16(v1[2] * p);
            a[7] = (short)f32_to_bf16(v1[3] * p);
            int cb = (kk * 64 + g * 16) ^ smask;    // swizzled byte col (0..127)
#pragma unroll
            for (int n = 0; n < 16; ++n) {
                short8 b = *(const short8*)(&ldsB[(n * 16 + rl) * 64 + (cb >> 1)]);
                acc[n] = __builtin_amdgcn_mfma_f32_16x16x32_bf16(a, b, acc[n], 0, 0, 0);
            }
        }
    }

    // epilogue: lane (rl,g) holds rows wm0+g*4+i, cols n*16+rl -> natural layout
#pragma unroll
    for (int n = 0; n < 16; ++n) {
        int c = n * 16 + rl;
#pragma unroll
        for (int i = 0; i < 4; ++i) {
            int rw = wm0 + g * 4 + i;
            if (rw < N) z[(size_t)rw * 256 + c] = f32_to_bf16(acc[n][i]);
        }
    }
}

// out[n] = rsqrt(max(deg,1)) * sum z[src] + bias; one wave per (node, col-half).
// gridDim.y = 2 column passes; quarter-wave per edge: 16 lanes x 16B = 256B half-row.
__global__ void k_agg(const unsigned short* __restrict__ z,
                      const int* __restrict__ cursor, const int* __restrict__ inc,
                      const int* __restrict__ eidx, const float* __restrict__ bias,
                      int N, float* __restrict__ out) {
    int node = blockIdx.x * 4 + (threadIdx.x >> 6);
    if (node >= N) return;
    int h    = blockIdx.y;           // column pass: cols h*128 .. h*128+127
    int lane = threadIdx.x & 63;
    int q    = lane >> 4;            // quarter 0..3 -> edge e+q
    int sl   = lane & 15;            // 16B chunk within the 256B half-row
    int deg  = inc[node];
    const int* ep = eidx + (cursor[node] - deg);   // cursor is END after fill
    const unsigned short* zh = z + h * 128 + sl * 8;

    float accA[8], accB[8];
#pragma unroll
    for (int j = 0; j < 8; ++j) { accA[j] = 0.f; accB[j] = 0.f; }

    int e = 0;
    for (; e + 8 <= deg; e += 8) {       // 8 edges, 2 gathers in flight
        int s0 = ep[e + q];
        int s1 = ep[e + 4 + q];
        ushort8 v0 = *(const ushort8*)(zh + (size_t)s0 * 256);
        ushort8 v1 = *(const ushort8*)(zh + (size_t)s1 * 256);
#pragma unroll
        for (int j = 0; j < 8; ++j) {
            accA[j] += bf2f(v0[j]);
            accB[j] += bf2f(v1[j]);
        }
    }
    for (; e < deg; e += 4) {            // tail: predicated quarters
        if (e + q < deg) {
            int s = ep[e + q];
            ushort8 v = *(const ushort8*)(zh + (size_t)s * 256);
#pragma unroll
            for (int j = 0; j < 8; ++j) accA[j] += bf2f(v[j]);
        }
    }
#pragma unroll
    for (int j = 0; j < 8; ++j) accA[j] += accB[j];
    // reduce across quarters (fixed sl): all lanes end with the full sum
#pragma unroll
    for (int j = 0; j < 8; ++j) accA[j] += __shfl_xor(accA[j], 16);
#pragma unroll
    for (int j = 0; j < 8; ++j) accA[j] += __shfl_xor(accA[j], 32);

    float post = rsqrtf((float)max(deg, 1));
    // lane (q,sl) writes cols h*128 + sl*8 + q*2 + {0,1}  -> contiguous per wave
    int c = h * 128 + sl * 8 + q * 2;
    floatx2 o;
    o[0] = accA[q * 2 + 0] * post + bias[c];
    o[1] = accA[q * 2 + 1] * post + bias[c + 1];
    __builtin_nontemporal_store(o, (floatx2*)(out + (size_t)node * 256 + c));
}

extern "C" void kernel_launch(void* const* d_in, const int* in_sizes, int n_in,
                              void* d_out, int out_size, void* d_ws, size_t ws_size,
                              hipStream_t stream) {
    const float* feat = (const float*)d_in[0];
    const int*   src  = (const int*)d_in[1];
    const int*   dst  = (const int*)d_in[2];
    const float* W    = (const float*)d_in[3];
    const float* bias = (const float*)d_in[4];
    float* out = (float*)d_out;

    const int D = 256;
    int N = in_sizes[0] / D;   // 100000
    int E = in_sizes[1];       // 1600000

    // workspace layout (256B aligned chunks), total ~58 MB
    char* ws = (char*)d_ws;
    size_t off = 0;
    auto alloc = [&](size_t bytes) -> void* {
        void* p = ws + off;
        off += (bytes + 255) & ~(size_t)255;
        return p;
    };
    int*            cnt    = (int*)alloc(((size_t)2 * N + 64) * sizeof(int)); // outc|inc|total
    int*            outc   = cnt;
    int*            inc    = cnt + N;
    int*            total  = cnt + 2 * N;
    int*            cursor = (int*)alloc((size_t)N * sizeof(int));
    int*            eidx   = (int*)alloc((size_t)E * sizeof(int));
    unsigned short* z      = (unsigned short*)alloc((size_t)N * D * sizeof(unsigned short));
    unsigned short* WT     = (unsigned short*)alloc((size_t)D * D * sizeof(unsigned short));
    (void)ws_size;

    hipMemsetAsync(cnt, 0, ((size_t)2 * N + 64) * sizeof(int), stream);

    int nbFill = (E + 1023) / 1024;          // 2 edges/thread at 512 threads
    int nbGemm = (N + 127) / 128;
    k_deg<<<(E + 511) / 512, 256, 0, stream>>>(src, dst, E, outc, inc);
    k_off<<<(N + 255) / 256, 256, 0, stream>>>(inc, N, total, cursor);
    k_wt <<<(D * D) / 256, 256, 0, stream>>>(W, WT);
    k_fg <<<nbFill + nbGemm, 512, 0, stream>>>(src, dst, E, cursor, eidx,
                                               feat, outc, WT, N, z, nbFill);
    k_agg<<<dim3((N + 3) / 4, 2), 256, 0, stream>>>(z, cursor, inc, eidx, bias, N, out);
}